// Round 27
// baseline (160.608 us; speedup 1.0000x reference)
//
#include <hip/hip_runtime.h>
#include <hip/hip_bf16.h>

#define N_ROWS 8192
#define DIM 256
#define R_BLK 64           // row-slots per block (4 waves x 16)
#define C_CHUNK 512        // cols per block
#define TILE_C 32          // cols per LDS tile
#define N_CHUNKS 16
#define N_ITERS (C_CHUNK / TILE_C)   // 16
#define N_PBLK 512         // prep blocks (16 rows each)
#define N_RBLK 128         // max rowblk groups

typedef __attribute__((ext_vector_type(4))) float f32x4;
typedef __attribute__((ext_vector_type(8))) short bf16x8;

__device__ __forceinline__ void gload_lds16(const void* g, void* l) {
    using gv = const __attribute__((address_space(1))) void*;
    using sv = __attribute__((address_space(3))) void*;
    __builtin_amdgcn_global_load_lds((gv)g, (sv)l, 16, 0, 0);
}

__device__ __forceinline__ ushort f2bf(float v) {
    __hip_bfloat16 h = __float2bfloat16(v);
    return *reinterpret_cast<ushort*>(&h);
}

// ---------------- Kernel A: normalize rows -> bf16 + per-block local compaction ----------------
// 512 blocks x 16 rows. NO atomics: block b writes cnt[b] + locally-compacted raw[b*16..].
// Blocks 0..127 also zero rb_cnt; block 0 zeroes done. Deterministic.
__global__ __launch_bounds__(256) void prep_kernel(const float* __restrict__ feat,
                                                   const float* __restrict__ ious,
                                                   const int* __restrict__ labels,
                                                   ushort* __restrict__ fhi,
                                                   int* __restrict__ raw,
                                                   int* __restrict__ cnt,
                                                   int* __restrict__ rb_cnt,
                                                   int* __restrict__ done) {
    if (threadIdx.x == 0) {
        if (blockIdx.x < N_RBLK) rb_cnt[blockIdx.x] = 0;
        if (blockIdx.x == 0) done[0] = 0;
    }
    const int wid  = threadIdx.x >> 6;
    const int lane = threadIdx.x & 63;
#pragma unroll
    for (int r4 = 0; r4 < 4; ++r4) {
        const int row = blockIdx.x * 16 + r4 * 4 + wid;
        const float4 x = reinterpret_cast<const float4*>(feat + (size_t)row * DIM)[lane];
        float ss = x.x * x.x + x.y * x.y + x.z * x.z + x.w * x.w;
#pragma unroll
        for (int off = 32; off; off >>= 1) ss += __shfl_xor(ss, off);
        const float inv = 1.0f / fmaxf(sqrtf(ss), 1e-12f);
        ushort4 h;
        h.x = f2bf(x.x * inv); h.y = f2bf(x.y * inv);
        h.z = f2bf(x.z * inv); h.w = f2bf(x.w * inv);
        reinterpret_cast<ushort4*>(fhi + (size_t)row * DIM)[lane] = h;
    }
    if (threadIdx.x < 64) {            // wave 0: local compaction of this block's 16 rows
        const int row = blockIdx.x * 16 + (lane & 15);
        const bool act = (lane < 16) && (labels[row] >= 0) && (ious[row] > 0.5f);
        const unsigned long long mb = __ballot(act);
        const int off = __popcll(mb & ((1ull << lane) - 1ull));
        if (act) raw[blockIdx.x * 16 + off] = row;
        if (lane == 0) cnt[blockIdx.x] = __popcll(mb);
    }
}

// ---------------- Kernel B: fused sim + mask + softmax partials + combine + mean ----------------
// grid = 2048: chunk = bid&15 (512 cols), rowblk = bid>>4 (64 active-row slots, 16/wave).
// Prologue: wave-0 shuffle scan of cnt[512] -> sex[] prefix.
// Single-barrier 2-phase K-loop, fragment-ordered B tile.
// Tail: threadfence-reduction — 16th chunk-arriver per rowblk combines its 64 rows;
// last rowblk-group (done counter) sums partT/partC in fixed order -> out. Deterministic.
__global__ __launch_bounds__(256, 4) void main_kernel(const ushort* __restrict__ fhi,
                                                      const float* __restrict__ ious,
                                                      const int* __restrict__ labels,
                                                      const int* __restrict__ raw,
                                                      const int* __restrict__ cnt,
                                                      float* __restrict__ ps_part,
                                                      float* __restrict__ as_part,
                                                      int* __restrict__ rb_cnt,
                                                      int* __restrict__ done,
                                                      float* __restrict__ partT,
                                                      float* __restrict__ partC,
                                                      float* __restrict__ out) {
    const int tid  = threadIdx.x;
    const int lane = tid & 63;

    __shared__ int sex[N_PBLK + 1];  // exclusive prefix of cnt
    if (tid < 64) {                  // wave-0 scan: 8 cnt values per lane
        int v[8], p[8];
        int lsum = 0;
#pragma unroll
        for (int k = 0; k < 8; ++k) { v[k] = cnt[lane * 8 + k]; p[k] = lsum; lsum += v[k]; }
        int inc = lsum;
#pragma unroll
        for (int off = 1; off < 64; off <<= 1) {
            const int t = __shfl_up(inc, off);
            if (lane >= off) inc += t;
        }
        const int base = inc - lsum;
        if (lane == 0) sex[0] = 0;
#pragma unroll
        for (int k = 0; k < 8; ++k) sex[lane * 8 + k + 1] = base + p[k] + v[k];
    }
    __syncthreads();
    const int nactive = sex[N_PBLK];

    const int bid    = blockIdx.x;
    const int rowblk = bid >> 4;
    const int rbase  = rowblk * R_BLK;
    if (nactive == 0) {                 // degenerate: reference returns 0
        if (bid == 0 && tid == 0) out[0] = 0.0f;
        return;
    }
    if (rbase >= nactive) return;      // block-uniform exit

    const int chunk = bid & (N_CHUNKS - 1);
    const int c0    = chunk * C_CHUNK;

    const int w    = tid >> 6;          // 0..3
    const int lrow = lane & 15;
    const int kg   = lane >> 4;         // 0..3
    const int s0   = rbase + w * 16;    // this wave's first row-slot

    // slot -> original row (binary search over exclusive prefix, 9 steps for 512)
    auto slot2row = [&](int s) {
        int lo = 0, hi = N_PBLK;
#pragma unroll
        for (int step = 0; step < 9; ++step) {
            const int mid = (lo + hi) >> 1;
            if (sex[mid] <= s) lo = mid; else hi = mid;
        }
        return raw[lo * 16 + (s - sex[lo])];
    };

    __shared__ bf16x8 bt[2][1024];          // 32 KB, double-buffered fragment-ordered B tile
    __shared__ int    lab_s[C_CHUNK];       // 2 KB
    __shared__ float  iou_s[C_CHUNK];       // 2 KB

#pragma unroll
    for (int i = tid; i < C_CHUNK; i += 256) {
        lab_s[i] = labels[c0 + i];
        iou_s[i] = ious[c0 + i];
    }

    // A fragments: one 16-row tile (gathered) x 256 k in registers (32 VGPR)
    bf16x8 av[8];
    {
        const int rowA = slot2row(min(s0 + lrow, nactive - 1));
        const ushort* pa = fhi + (size_t)rowA * DIM + kg * 8;
#pragma unroll
        for (int t = 0; t < 8; ++t) av[t] = *reinterpret_cast<const bf16x8*>(pa + t * 32);
    }

    // row metadata for the 4 row-slots this lane covers (C/D: col=lane&15, row=kg*4+r)
    int rowm[4]; int labi[4]; float ioui[4]; int livem = 0;
#pragma unroll
    for (int m = 0; m < 4; ++m) {
        const int slot = s0 + kg * 4 + m;
        const bool lv = slot < nactive;
        livem |= lv ? (1 << m) : 0;
        const int gi = slot2row(min(slot, nactive - 1));
        rowm[m] = gi;
        labi[m] = lv ? labels[gi] : -2;
        ioui[m] = ious[gi];
    }

    float ps[4] = {0.f,0.f,0.f,0.f}, as_[4] = {0.f,0.f,0.f,0.f};

    // staging in fragment order: LDS chunk L <- global fragment (half,t,lr,kg2)
    const char* fhib = (const char*)fhi;
    char* btb = (char*)&bt[0][0];
    auto stage = [&](int buf, int it) {
        const int jc = c0 + it * TILE_C;
#pragma unroll
        for (int iss = 0; iss < 4; ++iss) {
            const int L    = iss * 256 + tid;
            const int half = L >> 9;
            const int rem  = L & 511;
            const int t    = rem >> 6;
            const int lr   = (rem >> 2) & 15;
            const int kg2  = rem & 3;
            const char* src = fhib + (((size_t)(jc + half * 16 + lr)) << 9) + (kg2 * 16 + t * 64);
            char* dst = btb + buf * 16384 + iss * 4096 + tid * 16;
            gload_lds16(src, dst);
        }
    };

    stage(0, 0);
    __syncthreads();

    const float C1 = 14.42695041f;   // 10*log2(e): e = exp2(acc*C1 - C1) == exp(sim-10)
    int cur = 0;
    for (int it = 0; it < N_ITERS; ++it) {
        if (it + 1 < N_ITERS) stage(cur ^ 1, it + 1);   // loads land during compute below

        const int jcl = it * TILE_C;
        const int colg0 = c0 + jcl + lrow;
        const int colg1 = colg0 + 16;
        const int labj0 = lab_s[jcl + lrow];
        const int labj1 = lab_s[jcl + 16 + lrow];
        const float iouj0 = iou_s[jcl + lrow];
        const float iouj1 = iou_s[jcl + 16 + lrow];

        f32x4 acc0 = {0.f,0.f,0.f,0.f}, acc1 = {0.f,0.f,0.f,0.f};
        const char* lbase = btb + cur * 16384 + ((lrow * 4 + kg) << 4);
#pragma unroll
        for (int t = 0; t < 8; ++t) {
            bf16x8 b0 = *reinterpret_cast<const bf16x8*>(lbase + t * 1024);
            bf16x8 b1 = *reinterpret_cast<const bf16x8*>(lbase + 8192 + t * 1024);
            acc0 = __builtin_amdgcn_mfma_f32_16x16x32_bf16(av[t], b0, acc0, 0, 0, 0);
            acc1 = __builtin_amdgcn_mfma_f32_16x16x32_bf16(av[t], b1, acc1, 0, 0, 0);
        }

        // epilogue (active rows: hi_i true, ng_i false, fg_i true)
#pragma unroll
        for (int half = 0; half < 2; ++half) {
            const int colg = half ? colg1 : colg0;
            const int labj = half ? labj1 : labj0;
            const float iouj = half ? iouj1 : iouj0;
            const f32x4 acc = half ? acc1 : acc0;
            const bool fgj = labj >= 0;
            const bool hij = iouj > 0.5f;
#pragma unroll
            for (int m = 0; m < 4; ++m) {
                const bool same = (labi[m] == labj);
                const bool ioum = hij && (fabsf(iouj - ioui[m]) < 0.2f);
                const bool pf   = fgj && (rowm[m] != colg);
                const bool pos  = same && ioum && pf;
                const bool allm = pf && (ioum || !same);
                const float e = allm ? exp2f(fmaf(acc[m], C1, -C1)) : 0.0f;
                as_[m] += e;
                ps[m]  += pos ? e : 0.0f;
            }
        }
        asm volatile("s_waitcnt vmcnt(0)" ::: "memory");
        __builtin_amdgcn_s_barrier();
        __builtin_amdgcn_sched_barrier(0);
        cur ^= 1;
    }

    // reduce over the 16 lanes (lrow) holding col-slices of the same rows
#pragma unroll
    for (int off = 1; off < 16; off <<= 1) {
#pragma unroll
        for (int m = 0; m < 4; ++m) {
            ps[m]  += __shfl_xor(ps[m], off);
            as_[m] += __shfl_xor(as_[m], off);
        }
    }

    if (lrow == 0) {
#pragma unroll
        for (int m = 0; m < 4; ++m) {
            if ((livem >> m) & 1) {
                const int idx = chunk * N_ROWS + rowm[m];
                ps_part[idx] = ps[m];
                as_part[idx] = as_[m];
            }
        }
    }

    // ---- fused combine (threadFenceReduction pattern) ----
    __shared__ int amLast;
    __threadfence();
    __syncthreads();
    if (tid == 0) amLast = (atomicAdd(&rb_cnt[rowblk], 1) == N_CHUNKS - 1);
    __syncthreads();
    if (amLast) {
        __threadfence();   // acquire: other chunks' partials visible
        float loss = 0.f, vld = 0.f;
        if (tid < 64) {
            const int slot = rbase + tid;
            if (slot < nactive) {
                const int row = slot2row(slot);
                float P = 0.f, A = 0.f;
#pragma unroll
                for (int c = 0; c < N_CHUNKS; ++c) {
                    P += ps_part[c * N_ROWS + row];
                    A += as_part[c * N_ROWS + row];
                }
                const float psc = fminf(fmaxf(P, 1e-6f), 1e6f);
                const float asc = fminf(fmaxf(A, 1e-6f), 1e6f);
                const bool valid = (P > 0.0f) && (A > P);
                loss = valid ? fminf(__logf(asc) - __logf(psc), 10.0f) : 0.0f;
                vld  = valid ? 1.0f : 0.0f;
            }
#pragma unroll
            for (int off = 32; off; off >>= 1) {
                loss += __shfl_down(loss, off);
                vld  += __shfl_down(vld, off);
            }
            if (tid == 0) {
                partT[rowblk] = loss;
                partC[rowblk] = vld;
                __threadfence();
                const int nrb = (nactive + R_BLK - 1) / R_BLK;
                const int prev = atomicAdd(done, 1);
                if (prev == nrb - 1) {        // last rowblk finalizes (fixed order sum)
                    __threadfence();
                    float T = 0.f, C = 0.f;
                    for (int b = 0; b < nrb; ++b) { T += partT[b]; C += partC[b]; }
                    out[0] = (C > 0.f) ? (T / C) : 0.0f;
                }
            }
        }
    }
}

extern "C" void kernel_launch(void* const* d_in, const int* in_sizes, int n_in,
                              void* d_out, int out_size, void* d_ws, size_t ws_size,
                              hipStream_t stream) {
    const float* feat   = (const float*)d_in[0];
    const float* ious   = (const float*)d_in[1];
    const int*   labels = (const int*)d_in[2];
    float* out = (float*)d_out;

    ushort* fhi = (ushort*)d_ws;                                     // 4 MB
    float*  ps_part = (float*)(fhi + (size_t)N_ROWS * DIM);          // 512 KB
    float*  as_part = ps_part + (size_t)N_CHUNKS * N_ROWS;           // 512 KB
    int*    raw  = (int*)(as_part + (size_t)N_CHUNKS * N_ROWS);      // 32 KB
    int*    cnt  = raw + N_ROWS;                                     // 2 KB
    int*    rb_cnt = cnt + N_PBLK;                                   // 512 B
    int*    done = rb_cnt + N_RBLK;                                  // 4 B
    float*  partT = (float*)(done + 1);                              // 512 B
    float*  partC = partT + N_RBLK;                                  // 512 B

    prep_kernel<<<N_PBLK, 256, 0, stream>>>(feat, ious, labels, fhi, raw, cnt, rb_cnt, done);
    main_kernel<<<(N_ROWS / R_BLK) * N_CHUNKS, 256, 0, stream>>>(fhi, ious, labels,
                                                                 raw, cnt, ps_part, as_part,
                                                                 rb_cnt, done, partT, partC, out);
}

// Round 28
// 49.694 us; speedup vs baseline: 3.2319x; 3.2319x over previous
//
#include <hip/hip_runtime.h>
#include <hip/hip_bf16.h>

#define N_ROWS 8192
#define DIM 256
#define R_BLK 64           // row-slots per block (4 waves x 16)
#define C_CHUNK 512        // cols per block
#define TILE_C 32          // cols per LDS tile
#define N_CHUNKS 16
#define N_ITERS (C_CHUNK / TILE_C)   // 16
#define N_PBLK 512         // prep blocks (16 rows each)

typedef __attribute__((ext_vector_type(4))) float f32x4;
typedef __attribute__((ext_vector_type(8))) short bf16x8;

__device__ __forceinline__ void gload_lds16(const void* g, void* l) {
    using gv = const __attribute__((address_space(1))) void*;
    using sv = __attribute__((address_space(3))) void*;
    __builtin_amdgcn_global_load_lds((gv)g, (sv)l, 16, 0, 0);
}

__device__ __forceinline__ ushort f2bf(float v) {
    __hip_bfloat16 h = __float2bfloat16(v);
    return *reinterpret_cast<ushort*>(&h);
}

// ---------------- Kernel A: normalize rows -> bf16 + per-block local compaction ----------------
// 512 blocks x 16 rows. NO atomics: block b writes cnt[b] + locally-compacted raw[b*16..].
// Block 0 zeroes `done` for combine (stream-ordered). Deterministic.
__global__ __launch_bounds__(256) void prep_kernel(const float* __restrict__ feat,
                                                   const float* __restrict__ ious,
                                                   const int* __restrict__ labels,
                                                   ushort* __restrict__ fhi,
                                                   int* __restrict__ raw,
                                                   int* __restrict__ cnt,
                                                   int* __restrict__ done) {
    if (blockIdx.x == 0 && threadIdx.x == 0) done[0] = 0;
    const int wid  = threadIdx.x >> 6;
    const int lane = threadIdx.x & 63;
#pragma unroll
    for (int r4 = 0; r4 < 4; ++r4) {
        const int row = blockIdx.x * 16 + r4 * 4 + wid;
        const float4 x = reinterpret_cast<const float4*>(feat + (size_t)row * DIM)[lane];
        float ss = x.x * x.x + x.y * x.y + x.z * x.z + x.w * x.w;
#pragma unroll
        for (int off = 32; off; off >>= 1) ss += __shfl_xor(ss, off);
        const float inv = 1.0f / fmaxf(sqrtf(ss), 1e-12f);
        ushort4 h;
        h.x = f2bf(x.x * inv); h.y = f2bf(x.y * inv);
        h.z = f2bf(x.z * inv); h.w = f2bf(x.w * inv);
        reinterpret_cast<ushort4*>(fhi + (size_t)row * DIM)[lane] = h;
    }
    if (threadIdx.x < 64) {            // wave 0: local compaction of this block's 16 rows
        const int row = blockIdx.x * 16 + (lane & 15);
        const bool act = (lane < 16) && (labels[row] >= 0) && (ious[row] > 0.5f);
        const unsigned long long mb = __ballot(act);
        const int off = __popcll(mb & ((1ull << lane) - 1ull));
        if (act) raw[blockIdx.x * 16 + off] = row;
        if (lane == 0) cnt[blockIdx.x] = __popcll(mb);
    }
}

// ---------------- Kernel B: fused tiled sim + mask + fixed-max softmax partials ----------------
// grid = 2048: chunk = bid&15 (512 cols), rowblk = bid>>4 (64 active-row slots, 16/wave).
// Prologue: wave-0 shuffle scan of cnt[512] (8/lane) -> sex[] prefix; dead blocks exit fast.
// B tile in MFMA-FRAGMENT ORDER. Single-barrier 2-phase loop:
//   stage(next) -> compute(cur) -> vmcnt(0) [loads landed during compute] -> s_barrier.
// NOTE: NO block-wide __threadfence here — round-27 post-mortem: block-wide device-scope
// fences serialize at L2 (~4x kernel slowdown). Combine stays a separate kernel.
__global__ __launch_bounds__(256, 4) void main_kernel(const ushort* __restrict__ fhi,
                                                      const float* __restrict__ ious,
                                                      const int* __restrict__ labels,
                                                      const int* __restrict__ raw,
                                                      const int* __restrict__ cnt,
                                                      float* __restrict__ ps_part,
                                                      float* __restrict__ as_part) {
    const int tid  = threadIdx.x;
    const int lane = tid & 63;

    __shared__ int sex[N_PBLK + 1];  // exclusive prefix of cnt
    if (tid < 64) {                  // wave-0 scan: 8 cnt values per lane
        int v[8], p[8];
        int lsum = 0;
#pragma unroll
        for (int k = 0; k < 8; ++k) { v[k] = cnt[lane * 8 + k]; p[k] = lsum; lsum += v[k]; }
        int inc = lsum;
#pragma unroll
        for (int off = 1; off < 64; off <<= 1) {
            const int t = __shfl_up(inc, off);
            if (lane >= off) inc += t;
        }
        const int base = inc - lsum;          // exclusive prefix of this lane's group
        if (lane == 0) sex[0] = 0;
#pragma unroll
        for (int k = 0; k < 8; ++k) sex[lane * 8 + k + 1] = base + p[k] + v[k];
    }
    __syncthreads();
    const int nactive = sex[N_PBLK];

    const int bid   = blockIdx.x;
    const int rbase = (bid >> 4) * R_BLK;
    if (rbase >= nactive) return;      // block-uniform exit (single barrier above)

    const int chunk = bid & (N_CHUNKS - 1);
    const int c0    = chunk * C_CHUNK;

    const int w    = tid >> 6;          // 0..3
    const int lrow = lane & 15;
    const int kg   = lane >> 4;         // 0..3
    const int s0   = rbase + w * 16;    // this wave's first row-slot

    // slot -> original row (binary search over exclusive prefix, 9 steps for 512)
    auto slot2row = [&](int s) {
        int lo = 0, hi = N_PBLK;
#pragma unroll
        for (int step = 0; step < 9; ++step) {
            const int mid = (lo + hi) >> 1;
            if (sex[mid] <= s) lo = mid; else hi = mid;
        }
        return raw[lo * 16 + (s - sex[lo])];
    };

    __shared__ bf16x8 bt[2][1024];          // 32 KB, double-buffered fragment-ordered B tile
    __shared__ int    lab_s[C_CHUNK];       // 2 KB
    __shared__ float  iou_s[C_CHUNK];       // 2 KB

    // stage column metadata for this chunk (2 per thread)
#pragma unroll
    for (int i = tid; i < C_CHUNK; i += 256) {
        lab_s[i] = labels[c0 + i];
        iou_s[i] = ious[c0 + i];
    }

    // A fragments: one 16-row tile (gathered) x 256 k in registers (32 VGPR)
    bf16x8 av[8];
    {
        const int rowA = slot2row(min(s0 + lrow, nactive - 1));
        const ushort* pa = fhi + (size_t)rowA * DIM + kg * 8;
#pragma unroll
        for (int t = 0; t < 8; ++t) av[t] = *reinterpret_cast<const bf16x8*>(pa + t * 32);
    }

    // row metadata for the 4 row-slots this lane covers (C/D: col=lane&15, row=kg*4+r)
    int rowm[4]; int labi[4]; float ioui[4]; int livem = 0;
#pragma unroll
    for (int m = 0; m < 4; ++m) {
        const int slot = s0 + kg * 4 + m;
        const bool lv = slot < nactive;
        livem |= lv ? (1 << m) : 0;
        const int gi = slot2row(min(slot, nactive - 1));
        rowm[m] = gi;
        labi[m] = lv ? labels[gi] : -2;   // -2: matches no column label
        ioui[m] = ious[gi];
    }

    float ps[4] = {0.f,0.f,0.f,0.f}, as_[4] = {0.f,0.f,0.f,0.f};

    // staging in fragment order: LDS chunk L <- global fragment (half,t,lr,kg2)
    const char* fhib = (const char*)fhi;
    char* btb = (char*)&bt[0][0];
    auto stage = [&](int buf, int it) {
        const int jc = c0 + it * TILE_C;
#pragma unroll
        for (int iss = 0; iss < 4; ++iss) {
            const int L    = iss * 256 + tid;      // 0..1023
            const int half = L >> 9;
            const int rem  = L & 511;
            const int t    = rem >> 6;
            const int lr   = (rem >> 2) & 15;
            const int kg2  = rem & 3;
            const char* src = fhib + (((size_t)(jc + half * 16 + lr)) << 9) + (kg2 * 16 + t * 64);
            char* dst = btb + buf * 16384 + iss * 4096 + tid * 16;
            gload_lds16(src, dst);
        }
    };

    stage(0, 0);
    __syncthreads();    // prologue: metadata ds_writes + tile0 all resident

    const float C1 = 14.42695041f;   // 10*log2(e): e = exp2(acc*C1 - C1) == exp(sim-10)
    int cur = 0;
    for (int it = 0; it < N_ITERS; ++it) {
        if (it + 1 < N_ITERS) stage(cur ^ 1, it + 1);   // loads land during compute below

        const int jcl = it * TILE_C;
        const int colg0 = c0 + jcl + lrow;
        const int colg1 = colg0 + 16;
        const int labj0 = lab_s[jcl + lrow];
        const int labj1 = lab_s[jcl + 16 + lrow];
        const float iouj0 = iou_s[jcl + lrow];
        const float iouj1 = iou_s[jcl + 16 + lrow];

        f32x4 acc0 = {0.f,0.f,0.f,0.f}, acc1 = {0.f,0.f,0.f,0.f};
        const char* lbase = btb + cur * 16384 + ((lrow * 4 + kg) << 4);
#pragma unroll
        for (int t = 0; t < 8; ++t) {
            bf16x8 b0 = *reinterpret_cast<const bf16x8*>(lbase + t * 1024);
            bf16x8 b1 = *reinterpret_cast<const bf16x8*>(lbase + 8192 + t * 1024);
            acc0 = __builtin_amdgcn_mfma_f32_16x16x32_bf16(av[t], b0, acc0, 0, 0, 0);
            acc1 = __builtin_amdgcn_mfma_f32_16x16x32_bf16(av[t], b1, acc1, 0, 0, 0);
        }

        // epilogue (active rows: hi_i true, ng_i false, fg_i true):
        //   pos = same && iouj>0.5 && |d|<0.2 && fgj && i!=j
        //   allm = (fgj && i!=j) && (ioum || !same)
#pragma unroll
        for (int half = 0; half < 2; ++half) {
            const int colg = half ? colg1 : colg0;
            const int labj = half ? labj1 : labj0;
            const float iouj = half ? iouj1 : iouj0;
            const f32x4 acc = half ? acc1 : acc0;
            const bool fgj = labj >= 0;
            const bool hij = iouj > 0.5f;
#pragma unroll
            for (int m = 0; m < 4; ++m) {
                const bool same = (labi[m] == labj);
                const bool ioum = hij && (fabsf(iouj - ioui[m]) < 0.2f);
                const bool pf   = fgj && (rowm[m] != colg);
                const bool pos  = same && ioum && pf;
                const bool allm = pf && (ioum || !same);
                const float e = allm ? exp2f(fmaf(acc[m], C1, -C1)) : 0.0f;
                as_[m] += e;
                ps[m]  += pos ? e : 0.0f;
            }
        }
        // single barrier per iter: stage loads completed during compute -> vmcnt(0) ~free;
        // barrier guarantees (a) all waves' tile-(it+1) writes landed, (b) all reads of
        // buf `cur` done before iter it+1 stages tile it+2 into it.
        asm volatile("s_waitcnt vmcnt(0)" ::: "memory");
        __builtin_amdgcn_s_barrier();
        __builtin_amdgcn_sched_barrier(0);
        cur ^= 1;
    }

    // reduce over the 16 lanes (lrow) holding col-slices of the same rows
#pragma unroll
    for (int off = 1; off < 16; off <<= 1) {
#pragma unroll
        for (int m = 0; m < 4; ++m) {
            ps[m]  += __shfl_xor(ps[m], off);
            as_[m] += __shfl_xor(as_[m], off);
        }
    }

    if (lrow == 0) {
#pragma unroll
        for (int m = 0; m < 4; ++m) {
            if ((livem >> m) & 1) {
                const int idx = chunk * N_ROWS + rowm[m];
                ps_part[idx] = ps[m];
                as_part[idx] = as_[m];
            }
        }
    }
}

// ---------------- Kernel C: combine chunk partials -> per-row loss -> mean (fused) ----------------
// Fence/atomic issued by ONE thread in each of 32 blocks only (cheap, unlike round-27's
// block-wide fence).
__global__ __launch_bounds__(256) void combine_kernel(const float* __restrict__ ps_part,
                                                      const float* __restrict__ as_part,
                                                      const float* __restrict__ ious,
                                                      const int* __restrict__ labels,
                                                      float* __restrict__ partT,
                                                      float* __restrict__ partC,
                                                      int* __restrict__ done,
                                                      float* __restrict__ out) {
    const int tid = threadIdx.x;
    const int row = blockIdx.x * 256 + tid;
    const bool act = (labels[row] >= 0) && (ious[row] > 0.5f);
    float loss = 0.f, vld = 0.f;
    if (act) {
        float P = 0.f, A = 0.f;
#pragma unroll
        for (int c = 0; c < N_CHUNKS; ++c) {
            P += ps_part[c * N_ROWS + row];
            A += as_part[c * N_ROWS + row];
        }
        const float psc = fminf(fmaxf(P, 1e-6f), 1e6f);
        const float asc = fminf(fmaxf(A, 1e-6f), 1e6f);
        const bool valid = (P > 0.0f) && (A > P);
        loss = valid ? fminf(__logf(asc) - __logf(psc), 10.0f) : 0.0f;
        vld  = valid ? 1.0f : 0.0f;
    }
    float tl = loss, tc = vld;
#pragma unroll
    for (int off = 32; off; off >>= 1) { tl += __shfl_down(tl, off); tc += __shfl_down(tc, off); }
    __shared__ float sl[4], sc4[4];
    const int wid = tid >> 6;
    if ((tid & 63) == 0) { sl[wid] = tl; sc4[wid] = tc; }
    __syncthreads();
    if (tid == 0) {
        partT[blockIdx.x] = sl[0] + sl[1] + sl[2] + sl[3];
        partC[blockIdx.x] = sc4[0] + sc4[1] + sc4[2] + sc4[3];
        __threadfence();
        const int prev = atomicAdd(done, 1);
        if (prev == (int)gridDim.x - 1) {      // last block finalizes (fixed order: deterministic)
            __threadfence();
            float T = 0.f, C = 0.f;
#pragma unroll
            for (int b = 0; b < N_ROWS / 256; ++b) { T += partT[b]; C += partC[b]; }
            out[0] = (C > 0.f) ? (T / C) : 0.0f;
        }
    }
}

extern "C" void kernel_launch(void* const* d_in, const int* in_sizes, int n_in,
                              void* d_out, int out_size, void* d_ws, size_t ws_size,
                              hipStream_t stream) {
    const float* feat   = (const float*)d_in[0];
    const float* ious   = (const float*)d_in[1];
    const int*   labels = (const int*)d_in[2];
    float* out = (float*)d_out;

    ushort* fhi = (ushort*)d_ws;                                     // 4 MB
    float*  ps_part = (float*)(fhi + (size_t)N_ROWS * DIM);          // 512 KB
    float*  as_part = ps_part + (size_t)N_CHUNKS * N_ROWS;           // 512 KB
    int*    raw  = (int*)(as_part + (size_t)N_CHUNKS * N_ROWS);      // 32 KB
    int*    cnt  = raw + N_ROWS;                                     // 2 KB
    int*    done = cnt + N_PBLK;                                     // 4 B
    float*  partT = (float*)(done + 1);                              // 32 floats
    float*  partC = partT + (N_ROWS / 256);                          // 32 floats

    prep_kernel<<<N_PBLK, 256, 0, stream>>>(feat, ious, labels, fhi, raw, cnt, done);
    main_kernel<<<(N_ROWS / R_BLK) * N_CHUNKS, 256, 0, stream>>>(fhi, ious, labels,
                                                                 raw, cnt, ps_part, as_part);
    combine_kernel<<<N_ROWS / 256, 256, 0, stream>>>(ps_part, as_part, ious, labels,
                                                     partT, partC, done, out);
}